// Round 12
// baseline (325.750 us; speedup 1.0000x reference)
//
#include <hip/hip_runtime.h>
#include <math.h>

#define N_NODES 50000
#define N_PAD   50016                 // padded to 32-row gemm tiles
#define N_EDGES 800000
#define E_TOT   (N_EDGES + N_NODES)   // edges + self-loops = 850000
#define F_IN    256
#define NHEAD   8
#define CH      32
#define HC      256                   // NHEAD*CH
#define OUT_C   40
#define NEG_SLOPE 0.2f
#define CAP     64                    // bucket capacity per dst (deg~Pois(16)+1)
#define G_WCVT  ((HC * F_IN + 255) / 256)            // 256 (W1^T only now)
#define NRANGE  8                     // XCD count: dst-range affinity bins
#define RANGE_SZ (N_NODES / NRANGE)   // 6250
#define BIN_CHUNK 2048
#define G_BINCH ((E_TOT + BIN_CHUNK - 1) / BIN_CHUNK)   // 416
#define G_BIN   (G_BINCH * NRANGE)                      // 3328
#define G_GEMM  (N_PAD / 32)                            // 1563

typedef unsigned short u16;
typedef unsigned int   u32;
typedef unsigned char  u8;
typedef __attribute__((ext_vector_type(8))) short bf16x8;   // 4 VGPRs
typedef __attribute__((ext_vector_type(4))) float f32x4;
typedef __attribute__((ext_vector_type(2))) float f32x2;

__device__ __forceinline__ u16 f2bf(float f) {
    union { u32 u; float f; } x; x.f = f;
    u32 u = x.u;
    return (u16)((u + 0x7fffu + ((u >> 16) & 1u)) >> 16);   // round-nearest-even
}
__device__ __forceinline__ float bflo(u32 v) {
    union { u32 u; float f; } x; x.u = v << 16; return x.f;
}
// fp8 e4m3 encode/decode — gfx950 native
__device__ __forceinline__ u8 f2fp8(float f) {
    return (u8)(__builtin_amdgcn_cvt_pk_fp8_f32(f, f, 0, false) & 0xff);
}

// ht8 layers are fp8 e4m3 head-major: ht8[node*256 + h*32 + c].
// r27: depth-4 prefetch REFUTED (60.0 vs 57.3, VGPR 36 cut occupancy; FETCH
// unchanged -> attn is at its service-rate floor FETCH/1.9TB/s). Reverted to
// the triple-confirmed r7 depth-2 body. NEW: gemm2 fused into attn1's
// epilogue PER-WAVE (no cross-wave barriers after entry — unlike r8's failed
// tail-coupled fusion): wave computes its dst's hmid row, ELU+bias, matvec
// with LDS-staged W2 (16KB, staged once behind the single entry barrier),
// fp8-store to ht8b + layer-2 alpha in-register. Kills gemm2 launch + hmid
// round-trip; hrow stays fp32 through the matvec.

// ===== prep: XCD-affine binned bucket-scatter + W1^T cvt (one launch)
__global__ __launch_bounds__(256) void prep_kernel(const int* __restrict__ ei,
        int* __restrict__ cursor, u16* __restrict__ csr_src,
        const float* __restrict__ W1, u16* __restrict__ Wt) {
    int b = blockIdx.x;
    if (b < G_BIN) {                  // binned one-pass scatter
        const int r  = b & (NRANGE - 1);
        const int ch = b >> 3;
        const int lo = r * RANGE_SZ, hi = lo + RANGE_SZ;
        int j0 = ch * BIN_CHUNK + threadIdx.x;
        #pragma unroll
        for (int i = 0; i < BIN_CHUNK / 256; ++i) {
            int j = j0 + i * 256;
            if (j < E_TOT) {
                int d = (j < N_EDGES) ? ei[N_EDGES + j] : (j - N_EDGES);
                if (d >= lo && d < hi) {
                    int s = (j < N_EDGES) ? ei[j] : d;
                    int pos = atomicAdd(&cursor[d], 1);
                    if (pos < CAP) csr_src[d * CAP + pos] = (u16)s;
                }
            }
        }
    } else {
        int t = (b - G_BIN) * 256 + threadIdx.x;     // 65536 total
        int n = t & 255, k = t >> 8;                 // coalesced reads
        Wt[(size_t)n * F_IN + k] = f2bf(W1[(size_t)k * HC + n]);
    }
}

// ===== GEMM1 epilogue: fp8 ht8 store + FUSED layer-1 alpha.
__device__ __forceinline__ void gemm_epilogue(f32x4 acc[2][4], int row0, int quad,
        int l16, int nb, const float* __restrict__ a_src,
        const float* __restrict__ a_dst, u8* __restrict__ ht8,
        float* __restrict__ asrc, float* __restrict__ adst) {
    #pragma unroll
    for (int m = 0; m < 2; ++m) {
        #pragma unroll
        for (int r = 0; r < 4; ++r) {
            int row = row0 + m * 16 + quad * 4 + r;
            if (row < N_NODES) {
                u8* hr = ht8 + (size_t)row * HC;
                #pragma unroll
                for (int n = 0; n < 4; ++n)
                    hr[nb + n * 16 + l16] = f2fp8(acc[m][n][r]);
            }
        }
    }
    const int hA = nb >> 5;
    const float sA0 = a_src[hA * 32 + l16],       sA1 = a_src[hA * 32 + 16 + l16];
    const float sB0 = a_src[(hA + 1) * 32 + l16], sB1 = a_src[(hA + 1) * 32 + 16 + l16];
    const float dA0 = a_dst[hA * 32 + l16],       dA1 = a_dst[hA * 32 + 16 + l16];
    const float dB0 = a_dst[(hA + 1) * 32 + l16], dB1 = a_dst[(hA + 1) * 32 + 16 + l16];
    #pragma unroll
    for (int m = 0; m < 2; ++m) {
        #pragma unroll
        for (int r = 0; r < 4; ++r) {
            float pa = acc[m][0][r] * sA0 + acc[m][1][r] * sA1;
            float pb = acc[m][2][r] * sB0 + acc[m][3][r] * sB1;
            float qa = acc[m][0][r] * dA0 + acc[m][1][r] * dA1;
            float qb = acc[m][2][r] * dB0 + acc[m][3][r] * dB1;
            #pragma unroll
            for (int off = 1; off < 16; off <<= 1) {
                pa += __shfl_xor(pa, off, 64);
                pb += __shfl_xor(pb, off, 64);
                qa += __shfl_xor(qa, off, 64);
                qb += __shfl_xor(qb, off, 64);
            }
            int row = row0 + m * 16 + quad * 4 + r;
            if (l16 == 0 && row < N_NODES) {
                asrc[row * NHEAD + hA]     = pa;
                asrc[row * NHEAD + hA + 1] = pb;
                adst[row * NHEAD + hA]     = qa;
                adst[row * NHEAD + hA + 1] = qb;
            }
        }
    }
}

// ================= GEMM1: ht8a = fp8(x @ W1) + fused alpha, LDS-staged A.
__global__ __launch_bounds__(256) void gemm1_mfma(const float* __restrict__ x,
        const u16* __restrict__ Wt, const float* __restrict__ a_src,
        const float* __restrict__ a_dst, u8* __restrict__ ht8,
        float* __restrict__ asrc, float* __restrict__ adst) {
    __shared__ u16 As[32 * 256];          // 16 KB bf16, swizzled
    const int row0 = blockIdx.x * 32;
    const int t    = threadIdx.x;

    {   // stage: 8 threads per row, float4-contiguous per wave
        const int r   = t >> 3;                       // 0..31
        const int sub = t & 7;
        const int gr  = min(row0 + r, N_NODES - 1);   // clamp pad rows
        const float4* xr = (const float4*)(x + (size_t)gr * F_IN);
        const int sw = (r & 7) << 4;
        char* Ar = (char*)As + r * 512;
        #pragma unroll
        for (int i = 0; i < 8; ++i) {
            int f4 = i * 8 + sub;                     // float4 idx 0..63
            float4 v = xr[f4];
            u32 lo = (u32)f2bf(v.x) | ((u32)f2bf(v.y) << 16);
            u32 hi = (u32)f2bf(v.z) | ((u32)f2bf(v.w) << 16);
            *(uint2*)(Ar + ((f4 * 8) ^ sw)) = make_uint2(lo, hi);
        }
    }
    __syncthreads();

    const int wave = t >> 6;
    const int lane = t & 63;
    const int l16  = lane & 15;
    const int quad = lane >> 4;
    const int nb   = wave * 64;
    const int swr  = (l16 & 7) << 4;
    const char* Ab = (const char*)As;

    f32x4 acc[2][4];
    #pragma unroll
    for (int m = 0; m < 2; ++m)
        #pragma unroll
        for (int n = 0; n < 4; ++n) acc[m][n] = (f32x4){0.f, 0.f, 0.f, 0.f};

    const u16* bp = Wt + (size_t)(nb + l16) * F_IN;   // N-tile stride 16*F_IN

    #pragma unroll 1
    for (int k0 = 0; k0 < F_IN; k0 += 32) {
        const int ko = k0 + quad * 8;
        bf16x8 a0 = *(const bf16x8*)(Ab + l16 * 512 + ((ko * 2) ^ swr));
        bf16x8 a1 = *(const bf16x8*)(Ab + (16 + l16) * 512 + ((ko * 2) ^ swr));
        bf16x8 b0 = *(const bf16x8*)(bp + 0 * 16 * F_IN + ko);
        bf16x8 b1 = *(const bf16x8*)(bp + 1 * 16 * F_IN + ko);
        bf16x8 b2 = *(const bf16x8*)(bp + 2 * 16 * F_IN + ko);
        bf16x8 b3 = *(const bf16x8*)(bp + 3 * 16 * F_IN + ko);
        acc[0][0] = __builtin_amdgcn_mfma_f32_16x16x32_bf16(a0, b0, acc[0][0], 0, 0, 0);
        acc[0][1] = __builtin_amdgcn_mfma_f32_16x16x32_bf16(a0, b1, acc[0][1], 0, 0, 0);
        acc[0][2] = __builtin_amdgcn_mfma_f32_16x16x32_bf16(a0, b2, acc[0][2], 0, 0, 0);
        acc[0][3] = __builtin_amdgcn_mfma_f32_16x16x32_bf16(a0, b3, acc[0][3], 0, 0, 0);
        acc[1][0] = __builtin_amdgcn_mfma_f32_16x16x32_bf16(a1, b0, acc[1][0], 0, 0, 0);
        acc[1][1] = __builtin_amdgcn_mfma_f32_16x16x32_bf16(a1, b1, acc[1][1], 0, 0, 0);
        acc[1][2] = __builtin_amdgcn_mfma_f32_16x16x32_bf16(a1, b2, acc[1][2], 0, 0, 0);
        acc[1][3] = __builtin_amdgcn_mfma_f32_16x16x32_bf16(a1, b3, acc[1][3], 0, 0, 0);
    }
    gemm_epilogue(acc, row0, quad, l16, nb, a_src, a_dst, ht8, asrc, adst);
}

// ================= attn layer 1 + FUSED gemm2 + layer-2 alpha.
// Gather loop = r7-proven depth-2 body. Epilogue is per-wave (no cross-wave
// sync after the single entry barrier): hmid row -> LDS (wave-private),
// h2 = ELU(0.125*row + b1) @ W2 (LDS-staged bf16), fp8 -> ht8b, alpha2.
// Grid is exactly 50000 waves -> entry barrier is divergence-safe.
__global__ __launch_bounds__(256) void attn1_fused_kernel(
        const int* __restrict__ degp, const u16* __restrict__ csr_src,
        const float* __restrict__ asrc, const float* __restrict__ adst,
        const u8* __restrict__ ht8, const float* __restrict__ b1,
        const float* __restrict__ W2, const float* __restrict__ a_src2,
        const float* __restrict__ a_dst2, u8* __restrict__ ht8b,
        float* __restrict__ asrc2, float* __restrict__ adst2) {
    __shared__ u16  W2s[CH * HC];        // 16 KB bf16, [k][n] (= W2's layout)
    __shared__ float sas2[HC], sad2[HC]; // 2 KB
    __shared__ float bs1[CH];            // 128 B
    __shared__ float hrow_s[4][CH];      // 512 B, wave-private rows

    {   // ---- stage W2 (fp32 -> bf16, coalesced), alpha2 tables, b1 ----
        for (int i = threadIdx.x; i < CH * HC / 8; i += 256) {   // 1024 iters
            const float4* wp = (const float4*)W2 + (size_t)i * 2;
            float4 v0 = wp[0], v1 = wp[1];
            u32 p0 = (u32)f2bf(v0.x) | ((u32)f2bf(v0.y) << 16);
            u32 p1 = (u32)f2bf(v0.z) | ((u32)f2bf(v0.w) << 16);
            u32 p2 = (u32)f2bf(v1.x) | ((u32)f2bf(v1.y) << 16);
            u32 p3 = (u32)f2bf(v1.z) | ((u32)f2bf(v1.w) << 16);
            ((uint4*)W2s)[i] = make_uint4(p0, p1, p2, p3);
        }
        if (threadIdx.x < HC) {
            sas2[threadIdx.x] = a_src2[threadIdx.x];
            sad2[threadIdx.x] = a_dst2[threadIdx.x];
        }
        if (threadIdx.x < CH) bs1[threadIdx.x] = b1[threadIdx.x];
    }
    __syncthreads();                     // the ONLY barrier

    const int dst  = (blockIdx.x * 256 + threadIdx.x) >> 6;   // exact cover
    const int lane = threadIdx.x & 63;
    const int w4   = threadIdx.x >> 6;
    const int q    = lane >> 4;
    const int l16  = lane & 15;
    const int h    = l16 >> 1;
    const float ad_own = adst[dst * NHEAD + h];
    const u8* hbase = ht8 + l16 * 16;

    f32x2 acc2[8];
    #pragma unroll
    for (int i = 0; i < 8; ++i) acc2[i] = (f32x2){0.f, 0.f};
    float wsum = 0.f;

    const int cnt = min(degp[dst], CAP);
    const int p0 = dst * CAP, p1 = p0 + cnt;
    const int nt = (cnt + 7) >> 3;

    float asA = -1e30f, asB = -1e30f;
    uint4 hvA = make_uint4(0u, 0u, 0u, 0u), hvB = make_uint4(0u, 0u, 0u, 0u);
    int e = p0 + q;
    if (e < p1) {
        int s = (int)csr_src[e];
        asA = asrc[s * NHEAD + h];
        hvA = *(const uint4*)(hbase + ((size_t)s << 8));
    }
    if (e + 4 < p1) {
        int s = (int)csr_src[e + 4];
        asB = asrc[s * NHEAD + h];
        hvB = *(const uint4*)(hbase + ((size_t)s << 8));
    }

    for (int it = 0; it < nt; ++it) {
        float aA = asA; uint4 hA = hvA;
        float aB = asB; uint4 hB = hvB;
        asA = -1e30f; asB = -1e30f;
        if (e + 8 < p1) {
            int s = (int)csr_src[e + 8];
            asA = asrc[s * NHEAD + h];
            hvA = *(const uint4*)(hbase + ((size_t)s << 8));
        }
        if (e + 12 < p1) {
            int s = (int)csr_src[e + 12];
            asB = asrc[s * NHEAD + h];
            hvB = *(const uint4*)(hbase + ((size_t)s << 8));
        }
        {
            float x = aA + ad_own;
            x = x > 0.f ? x : NEG_SLOPE * x;
            float w = __expf(x);
            wsum += w;
            f32x2 w2; w2.x = w; w2.y = w;
            acc2[0] = __builtin_elementwise_fma(w2, __builtin_amdgcn_cvt_pk_f32_fp8(hA.x, false), acc2[0]);
            acc2[1] = __builtin_elementwise_fma(w2, __builtin_amdgcn_cvt_pk_f32_fp8(hA.x, true ), acc2[1]);
            acc2[2] = __builtin_elementwise_fma(w2, __builtin_amdgcn_cvt_pk_f32_fp8(hA.y, false), acc2[2]);
            acc2[3] = __builtin_elementwise_fma(w2, __builtin_amdgcn_cvt_pk_f32_fp8(hA.y, true ), acc2[3]);
            acc2[4] = __builtin_elementwise_fma(w2, __builtin_amdgcn_cvt_pk_f32_fp8(hA.z, false), acc2[4]);
            acc2[5] = __builtin_elementwise_fma(w2, __builtin_amdgcn_cvt_pk_f32_fp8(hA.z, true ), acc2[5]);
            acc2[6] = __builtin_elementwise_fma(w2, __builtin_amdgcn_cvt_pk_f32_fp8(hA.w, false), acc2[6]);
            acc2[7] = __builtin_elementwise_fma(w2, __builtin_amdgcn_cvt_pk_f32_fp8(hA.w, true ), acc2[7]);
        }
        {
            float x = aB + ad_own;
            x = x > 0.f ? x : NEG_SLOPE * x;
            float w = __expf(x);
            wsum += w;
            f32x2 w2; w2.x = w; w2.y = w;
            acc2[0] = __builtin_elementwise_fma(w2, __builtin_amdgcn_cvt_pk_f32_fp8(hB.x, false), acc2[0]);
            acc2[1] = __builtin_elementwise_fma(w2, __builtin_amdgcn_cvt_pk_f32_fp8(hB.x, true ), acc2[1]);
            acc2[2] = __builtin_elementwise_fma(w2, __builtin_amdgcn_cvt_pk_f32_fp8(hB.y, false), acc2[2]);
            acc2[3] = __builtin_elementwise_fma(w2, __builtin_amdgcn_cvt_pk_f32_fp8(hB.y, true ), acc2[3]);
            acc2[4] = __builtin_elementwise_fma(w2, __builtin_amdgcn_cvt_pk_f32_fp8(hB.z, false), acc2[4]);
            acc2[5] = __builtin_elementwise_fma(w2, __builtin_amdgcn_cvt_pk_f32_fp8(hB.z, true ), acc2[5]);
            acc2[6] = __builtin_elementwise_fma(w2, __builtin_amdgcn_cvt_pk_f32_fp8(hB.w, false), acc2[6]);
            acc2[7] = __builtin_elementwise_fma(w2, __builtin_amdgcn_cvt_pk_f32_fp8(hB.w, true ), acc2[7]);
        }
        e += 8;
    }

    // ---- fold quarters, normalize, head-sum (classic) ----
    #pragma unroll
    for (int i = 0; i < 8; ++i) {
        acc2[i].x += __shfl_xor(acc2[i].x, 16, 64);
        acc2[i].y += __shfl_xor(acc2[i].y, 16, 64);
        acc2[i].x += __shfl_xor(acc2[i].x, 32, 64);
        acc2[i].y += __shfl_xor(acc2[i].y, 32, 64);
    }
    wsum += __shfl_xor(wsum, 16, 64);
    wsum += __shfl_xor(wsum, 32, 64);
    float winv = 1.0f / wsum;
    f32x2 winv2; winv2.x = winv; winv2.y = winv;
    #pragma unroll
    for (int i = 0; i < 8; ++i) acc2[i] *= winv2;
    #pragma unroll
    for (int i = 0; i < 8; ++i) {
        acc2[i].x += __shfl_xor(acc2[i].x, 2, 64);
        acc2[i].y += __shfl_xor(acc2[i].y, 2, 64);
        acc2[i].x += __shfl_xor(acc2[i].x, 4, 64);
        acc2[i].y += __shfl_xor(acc2[i].y, 4, 64);
        acc2[i].x += __shfl_xor(acc2[i].x, 8, 64);
        acc2[i].y += __shfl_xor(acc2[i].y, 8, 64);
    }

    // ---- wave-private hmid row -> LDS (ELU(0.125x + b1)); same-wave LDS
    // ordering, no barrier needed ----
    if (lane < 2) {
        const int c0 = lane * 16;
        #pragma unroll
        for (int i = 0; i < 8; ++i) {
            float v0 = acc2[i].x * 0.125f + bs1[c0 + 2 * i];
            float v1 = acc2[i].y * 0.125f + bs1[c0 + 2 * i + 1];
            v0 = v0 > 0.f ? v0 : (__expf(v0) - 1.f);
            v1 = v1 > 0.f ? v1 : (__expf(v1) - 1.f);
            hrow_s[w4][c0 + 2 * i]     = v0;
            hrow_s[w4][c0 + 2 * i + 1] = v1;
        }
    }

    // ---- fused gemm2: lane computes h2 channels lane*4 .. +3 ----
    float o0 = 0.f, o1 = 0.f, o2 = 0.f, o3 = 0.f;
    const u16* wb = W2s + lane * 4;      // [k][n]: row stride HC
    #pragma unroll
    for (int k = 0; k < CH; ++k) {
        uint2 wv = *(const uint2*)(wb + k * HC);     // 4 bf16 (ds_read_b64)
        float hk = hrow_s[w4][k];                    // wave-uniform broadcast
        o0 += hk * bflo(wv.x & 0xffffu);
        o1 += hk * bflo(wv.x >> 16);
        o2 += hk * bflo(wv.y & 0xffffu);
        o3 += hk * bflo(wv.y >> 16);
    }

    // ---- fp8 store (coalesced u32 per lane) ----
    u32 lo = __builtin_amdgcn_cvt_pk_fp8_f32(o0, o1, 0, false) & 0xffffu;
    u32 hi = __builtin_amdgcn_cvt_pk_fp8_f32(o2, o3, 0, false) & 0xffffu;
    *(u32*)(ht8b + (size_t)dst * HC + lane * 4) = lo | (hi << 16);

    // ---- layer-2 alpha: head h2 = lane>>3, 8-lane xor fold ----
    const int h2 = lane >> 3;
    const float* s2 = sas2 + h2 * CH + (lane & 7) * 4;
    const float* d2 = sad2 + h2 * CH + (lane & 7) * 4;
    float pa = o0 * s2[0] + o1 * s2[1] + o2 * s2[2] + o3 * s2[3];
    float qa = o0 * d2[0] + o1 * d2[1] + o2 * d2[2] + o3 * d2[3];
    pa += __shfl_xor(pa, 1, 64); qa += __shfl_xor(qa, 1, 64);
    pa += __shfl_xor(pa, 2, 64); qa += __shfl_xor(qa, 2, 64);
    pa += __shfl_xor(pa, 4, 64); qa += __shfl_xor(qa, 4, 64);
    if ((lane & 7) == 0) {
        asrc2[dst * NHEAD + h2] = pa;
        adst2[dst * NHEAD + h2] = qa;
    }
}

// ================= attn layer 2 (classic r7 body): ht8b -> hout
__global__ __launch_bounds__(256) void attn_kernel(const int* __restrict__ degp,
        const u16* __restrict__ csr_src, const float* __restrict__ asrc,
        const float* __restrict__ adst, const u8* __restrict__ ht8,
        const float* __restrict__ b, u16* __restrict__ out) {
    const int wid = (blockIdx.x * 256 + threadIdx.x) >> 6;   // dst node
    if (wid >= N_NODES) return;
    const int dst  = wid;
    const int lane = threadIdx.x & 63;
    const int q    = lane >> 4;          // quarter -> edge offset
    const int l16  = lane & 15;
    const int h    = l16 >> 1;           // owned head
    const float ad_own = adst[dst * NHEAD + h];
    const u8* hbase = ht8 + l16 * 16;    // this lane's 16B slice of each row

    f32x2 acc2[8];
    #pragma unroll
    for (int i = 0; i < 8; ++i) acc2[i] = (f32x2){0.f, 0.f};
    float wsum = 0.f;

    const int cnt = min(degp[dst], CAP);
    const int p0 = dst * CAP, p1 = p0 + cnt;
    const int nt = (cnt + 7) >> 3;       // uniform trips (8 edges per trip)

    float asA = -1e30f, asB = -1e30f;
    uint4 hvA = make_uint4(0u, 0u, 0u, 0u), hvB = make_uint4(0u, 0u, 0u, 0u);
    int e = p0 + q;                      // this quarter's edges: stride 4
    if (e < p1) {
        int s = (int)csr_src[e];
        asA = asrc[s * NHEAD + h];
        hvA = *(const uint4*)(hbase + ((size_t)s << 8));
    }
    if (e + 4 < p1) {
        int s = (int)csr_src[e + 4];
        asB = asrc[s * NHEAD + h];
        hvB = *(const uint4*)(hbase + ((size_t)s << 8));
    }

    for (int it = 0; it < nt; ++it) {
        float aA = asA; uint4 hA = hvA;
        float aB = asB; uint4 hB = hvB;
        asA = -1e30f; asB = -1e30f;
        if (e + 8 < p1) {                 // prefetch next trip (predicated)
            int s = (int)csr_src[e + 8];
            asA = asrc[s * NHEAD + h];
            hvA = *(const uint4*)(hbase + ((size_t)s << 8));
        }
        if (e + 12 < p1) {
            int s = (int)csr_src[e + 12];
            asB = asrc[s * NHEAD + h];
            hvB = *(const uint4*)(hbase + ((size_t)s << 8));
        }
        {   // consume A (edge e); invalid slots: w==0, finite hv -> no-op
            float x = aA + ad_own;
            x = x > 0.f ? x : NEG_SLOPE * x;
            float w = __expf(x);
            wsum += w;
            f32x2 w2; w2.x = w; w2.y = w;
            acc2[0] = __builtin_elementwise_fma(w2, __builtin_amdgcn_cvt_pk_f32_fp8(hA.x, false), acc2[0]);
            acc2[1] = __builtin_elementwise_fma(w2, __builtin_amdgcn_cvt_pk_f32_fp8(hA.x, true ), acc2[1]);
            acc2[2] = __builtin_elementwise_fma(w2, __builtin_amdgcn_cvt_pk_f32_fp8(hA.y, false), acc2[2]);
            acc2[3] = __builtin_elementwise_fma(w2, __builtin_amdgcn_cvt_pk_f32_fp8(hA.y, true ), acc2[3]);
            acc2[4] = __builtin_elementwise_fma(w2, __builtin_amdgcn_cvt_pk_f32_fp8(hA.z, false), acc2[4]);
            acc2[5] = __builtin_elementwise_fma(w2, __builtin_amdgcn_cvt_pk_f32_fp8(hA.z, true ), acc2[5]);
            acc2[6] = __builtin_elementwise_fma(w2, __builtin_amdgcn_cvt_pk_f32_fp8(hA.w, false), acc2[6]);
            acc2[7] = __builtin_elementwise_fma(w2, __builtin_amdgcn_cvt_pk_f32_fp8(hA.w, true ), acc2[7]);
        }
        {   // consume B (edge e+4)
            float x = aB + ad_own;
            x = x > 0.f ? x : NEG_SLOPE * x;
            float w = __expf(x);
            wsum += w;
            f32x2 w2; w2.x = w; w2.y = w;
            acc2[0] = __builtin_elementwise_fma(w2, __builtin_amdgcn_cvt_pk_f32_fp8(hB.x, false), acc2[0]);
            acc2[1] = __builtin_elementwise_fma(w2, __builtin_amdgcn_cvt_pk_f32_fp8(hB.x, true ), acc2[1]);
            acc2[2] = __builtin_elementwise_fma(w2, __builtin_amdgcn_cvt_pk_f32_fp8(hB.y, false), acc2[2]);
            acc2[3] = __builtin_elementwise_fma(w2, __builtin_amdgcn_cvt_pk_f32_fp8(hB.y, true ), acc2[3]);
            acc2[4] = __builtin_elementwise_fma(w2, __builtin_amdgcn_cvt_pk_f32_fp8(hB.z, false), acc2[4]);
            acc2[5] = __builtin_elementwise_fma(w2, __builtin_amdgcn_cvt_pk_f32_fp8(hB.z, true ), acc2[5]);
            acc2[6] = __builtin_elementwise_fma(w2, __builtin_amdgcn_cvt_pk_f32_fp8(hB.w, false), acc2[6]);
            acc2[7] = __builtin_elementwise_fma(w2, __builtin_amdgcn_cvt_pk_f32_fp8(hB.w, true ), acc2[7]);
        }
        e += 8;
    }

    // ---- fold the four quarters (same (h,chblk), disjoint edges) ----
    #pragma unroll
    for (int i = 0; i < 8; ++i) {
        acc2[i].x += __shfl_xor(acc2[i].x, 16, 64);
        acc2[i].y += __shfl_xor(acc2[i].y, 16, 64);
        acc2[i].x += __shfl_xor(acc2[i].x, 32, 64);
        acc2[i].y += __shfl_xor(acc2[i].y, 32, 64);
    }
    wsum += __shfl_xor(wsum, 16, 64);
    wsum += __shfl_xor(wsum, 32, 64);

    // ---- per-head softmax normalize ----
    float winv = 1.0f / wsum;
    f32x2 winv2; winv2.x = winv; winv2.y = winv;
    #pragma unroll
    for (int i = 0; i < 8; ++i) acc2[i] *= winv2;

    // ---- sum over heads: lane = 2h + blk, fold bits 1..3 ----
    #pragma unroll
    for (int i = 0; i < 8; ++i) {
        acc2[i].x += __shfl_xor(acc2[i].x, 2, 64);
        acc2[i].y += __shfl_xor(acc2[i].y, 2, 64);
        acc2[i].x += __shfl_xor(acc2[i].x, 4, 64);
        acc2[i].y += __shfl_xor(acc2[i].y, 4, 64);
        acc2[i].x += __shfl_xor(acc2[i].x, 8, 64);
        acc2[i].y += __shfl_xor(acc2[i].y, 8, 64);
    }

    // ---- lane 0: channels 0..15, lane 1: channels 16..31 ----
    if (lane < 2) {
        const int c0 = lane * 16;
        const float4* bp4 = (const float4*)(b + c0);
        float4 b0 = bp4[0], b1 = bp4[1], b2 = bp4[2], b3 = bp4[3];
        float bb[16] = {b0.x, b0.y, b0.z, b0.w, b1.x, b1.y, b1.z, b1.w,
                        b2.x, b2.y, b2.z, b2.w, b3.x, b3.y, b3.z, b3.w};
        u32 d[8];
        #pragma unroll
        for (int i = 0; i < 8; ++i) {
            float v0 = acc2[i].x * 0.125f + bb[2 * i];
            float v1 = acc2[i].y * 0.125f + bb[2 * i + 1];
            v0 = v0 > 0.f ? v0 : (__expf(v0) - 1.f);
            v1 = v1 > 0.f ? v1 : (__expf(v1) - 1.f);
            d[i] = (u32)f2bf(v0) | ((u32)f2bf(v1) << 16);
        }
        uint4* op = (uint4*)(out + (size_t)dst * CH + c0);
        op[0] = make_uint4(d[0], d[1], d[2], d[3]);
        op[1] = make_uint4(d[4], d[5], d[6], d[7]);
    }
}

// ================= output head: 4 nodes/block (1 wave each), log_softmax
__global__ __launch_bounds__(256) void out_kernel(const u16* __restrict__ hf,
        const float* __restrict__ Wo, const float* __restrict__ bo,
        float* __restrict__ out) {
    const int wave = threadIdx.x >> 6;
    const int lane = threadIdx.x & 63;
    const int n    = blockIdx.x * 4 + wave;
    __shared__ float hs[4][CH];
    if (n < N_NODES && lane < CH) hs[wave][lane] = bflo((u32)hf[n * CH + lane]);
    __syncthreads();
    if (n >= N_NODES) return;
    float logit = -INFINITY;
    if (lane < OUT_C) {
        float a = bo[lane];
        #pragma unroll
        for (int k = 0; k < CH; ++k) a += hs[wave][k] * Wo[k * OUT_C + lane];
        logit = a;
    }
    float m = logit;
    #pragma unroll
    for (int off = 32; off; off >>= 1) m = fmaxf(m, __shfl_xor(m, off, 64));
    float ex = (lane < OUT_C) ? __expf(logit - m) : 0.f;
    float ssum = ex;
    #pragma unroll
    for (int off = 32; off; off >>= 1) ssum += __shfl_xor(ssum, off, 64);
    if (lane < OUT_C) out[(size_t)n * OUT_C + lane] = logit - m - __logf(ssum);
}

extern "C" void kernel_launch(void* const* d_in, const int* in_sizes, int n_in,
                              void* d_out, int out_size, void* d_ws, size_t ws_size,
                              hipStream_t stream) {
    const float* x      = (const float*)d_in[0];
    const int*   ei     = (const int*)  d_in[1];
    const float* W1     = (const float*)d_in[2];
    const float* a_src1 = (const float*)d_in[3];
    const float* a_dst1 = (const float*)d_in[4];
    const float* b1     = (const float*)d_in[5];
    const float* W2     = (const float*)d_in[6];
    const float* a_src2 = (const float*)d_in[7];
    const float* a_dst2 = (const float*)d_in[8];
    const float* b2     = (const float*)d_in[9];
    const float* Wo     = (const float*)d_in[10];
    const float* bo     = (const float*)d_in[11];
    float* out = (float*)d_out;

    // workspace carve-up (256B-aligned)
    char* ws = (char*)d_ws;
    size_t off = 0;
    auto carve = [&](size_t bytes) { char* p = ws + off; off += (bytes + 255) & ~(size_t)255; return p; };
    u8*    ht8a    = (u8*)   carve((size_t)N_NODES * HC);          // 12.8 MB (layer1 fp8)
    u8*    ht8b    = (u8*)   carve((size_t)N_NODES * HC);          // 12.8 MB (layer2 fp8)
    u16*   Wt      = (u16*)  carve((size_t)HC * F_IN * 2);         // 128 KB (bf16 W1^T)
    float* asrc    = (float*)carve((size_t)N_NODES * NHEAD * 4);   // 1.6 MB (layer1)
    float* adst    = (float*)carve((size_t)N_NODES * NHEAD * 4);
    float* asrc2   = (float*)carve((size_t)N_NODES * NHEAD * 4);   // 1.6 MB (layer2)
    float* adst2   = (float*)carve((size_t)N_NODES * NHEAD * 4);
    u16*   hout    = (u16*)  carve((size_t)N_NODES * CH * 2);      // 3.2 MB (bf16)
    int*   cursor  = (int*)  carve((size_t)N_NODES * 4);           // doubles as deg
    u16*   csr_src = (u16*)  carve((size_t)N_NODES * CAP * 2);     // 6.4 MB buckets

    const int g_prep  = G_BIN + G_WCVT;                      // 3584
    const int g_attn  = (N_NODES * 64 + 255) / 256;          // 12500 (wave/dst)
    const int g_out   = (N_NODES + 3) / 4;                   // 12500

    // ---------- prep: one-pass bucket CSR + W1^T ----------
    (void)hipMemsetAsync(cursor, 0, (size_t)N_NODES * 4, stream);
    prep_kernel<<<g_prep, 256, 0, stream>>>(ei, cursor, csr_src, W1, Wt);

    // ---------- layer 1: gemm1 (+alpha1), attn1 (+gemm2 +alpha2 fused) ----------
    gemm1_mfma<<<G_GEMM, 256, 0, stream>>>(x, Wt, a_src1, a_dst1, ht8a, asrc, adst);
    attn1_fused_kernel<<<g_attn, 256, 0, stream>>>(cursor, csr_src, asrc, adst,
                                                   ht8a, b1, W2, a_src2, a_dst2,
                                                   ht8b, asrc2, adst2);

    // ---------- layer 2: attn2 (classic) ----------
    attn_kernel<<<g_attn, 256, 0, stream>>>(cursor, csr_src, asrc2, adst2,
                                            ht8b, b2, hout);

    // ---------- output head ----------
    out_kernel<<<g_out, 256, 0, stream>>>(hout, Wo, bo, out);
}

// Round 13
// 317.172 us; speedup vs baseline: 1.0270x; 1.0270x over previous
//
#include <hip/hip_runtime.h>
#include <math.h>

#define N_NODES 50000
#define N_PAD   50016                 // padded to 32-row gemm tiles
#define N_EDGES 800000
#define E_TOT   (N_EDGES + N_NODES)   // edges + self-loops = 850000
#define F_IN    256
#define NHEAD   8
#define CH      32
#define HC      256                   // NHEAD*CH
#define OUT_C   40
#define NEG_SLOPE 0.2f
#define CAP     64                    // bucket capacity per dst (deg~Pois(16)+1)
#define G_WCVT  ((HC * F_IN + 255) / 256)            // 256
#define G_WCVT2 ((HC * CH + 255) / 256)              // 32
#define NRANGE  8                     // XCD count: dst-range affinity bins
#define RANGE_SZ (N_NODES / NRANGE)   // 6250
#define BIN_CHUNK 2048
#define G_BINCH ((E_TOT + BIN_CHUNK - 1) / BIN_CHUNK)   // 416
#define G_BIN   (G_BINCH * NRANGE)                      // 3328
#define G_GEMM  (N_PAD / 32)                            // 1563

typedef unsigned short u16;
typedef unsigned int   u32;
typedef unsigned char  u8;
typedef __attribute__((ext_vector_type(8))) short bf16x8;   // 4 VGPRs
typedef __attribute__((ext_vector_type(4))) float f32x4;
typedef __attribute__((ext_vector_type(2))) float f32x2;

__device__ __forceinline__ u16 f2bf(float f) {
    union { u32 u; float f; } x; x.f = f;
    u32 u = x.u;
    return (u16)((u + 0x7fffu + ((u >> 16) & 1u)) >> 16);   // round-nearest-even
}
__device__ __forceinline__ float bflo(u32 v) {
    union { u32 u; float f; } x; x.u = v << 16; return x.f;
}
// fp8 e4m3 encode (1 byte) / packed decode (2 floats per op) — gfx950 native
__device__ __forceinline__ u8 f2fp8(float f) {
    return (u8)(__builtin_amdgcn_cvt_pk_fp8_f32(f, f, 0, false) & 0xff);
}

// ht8 is fp8 e4m3 head-major: ht8[node*256 + h*32 + c].
// r28: RESTORE of the best-measured configuration (r7, 317.2us). r12's
// gemm2-into-attn1 fusion refuted (+28us net: ~1000 serial epilogue cycles
// per wave with only ~3 gather trips to hide them under — per-wave fusion
// pays for O(10)-op epilogues like alpha, not O(1000)-op matvecs). attn is
// at its compulsory-traffic service floor: FETCH 108MB = 8 XCDs x 12.8MB
// ht8 + csr/asrc, dur = FETCH / 1.9TB/s L2-miss service rate. Refuted
// levers: sort (r8), LDS out-fusion (r8), head-split XCD affinity (r9),
// scatter∥gemm1 co-schedule (r10), depth-4 prefetch (r11), gemm2 fusion
// (r12). Keepers: bucket CSR (r7), XCD-binned scatter (r4), LDS-staged
// gemm1 (r5/r6), alpha-in-gemm-epilogue (r5/r6), fp8 ht8 (r0 lineage).

// ===== prep: XCD-affine binned bucket-scatter + W1^T + W2^T cvt (one launch)
__global__ __launch_bounds__(256) void prep_kernel(const int* __restrict__ ei,
        int* __restrict__ cursor, u16* __restrict__ csr_src,
        const float* __restrict__ W1, u16* __restrict__ Wt,
        const float* __restrict__ W2, u16* __restrict__ W2t) {
    int b = blockIdx.x;
    if (b < G_BIN) {                  // binned one-pass scatter
        const int r  = b & (NRANGE - 1);
        const int ch = b >> 3;
        const int lo = r * RANGE_SZ, hi = lo + RANGE_SZ;
        int j0 = ch * BIN_CHUNK + threadIdx.x;
        #pragma unroll
        for (int i = 0; i < BIN_CHUNK / 256; ++i) {
            int j = j0 + i * 256;
            if (j < E_TOT) {
                int d = (j < N_EDGES) ? ei[N_EDGES + j] : (j - N_EDGES);
                if (d >= lo && d < hi) {
                    int s = (j < N_EDGES) ? ei[j] : d;
                    int pos = atomicAdd(&cursor[d], 1);
                    if (pos < CAP) csr_src[d * CAP + pos] = (u16)s;
                }
            }
        }
    } else if (b < G_BIN + G_WCVT) {
        int t = (b - G_BIN) * 256 + threadIdx.x;     // 65536 total
        int n = t & 255, k = t >> 8;                 // coalesced reads
        Wt[(size_t)n * F_IN + k] = f2bf(W1[(size_t)k * HC + n]);
    } else {
        int t = (b - G_BIN - G_WCVT) * 256 + threadIdx.x;  // 8192
        if (t >= HC * CH) return;
        int n = t & 255, k = t >> 8;
        W2t[(size_t)n * CH + k] = f2bf(W2[(size_t)k * HC + n]);
    }
}

// ===== shared GEMM epilogue: fp8 ht8 store + FUSED alpha (per-row per-head
// dot with a_src/a_dst). Wave covers heads hA=nb>>5 (n=0,1) and hA+1 (n=2,3);
// channel c = n*16 + l16. Quad-local 16-lane xor-reduce; l16==0 stores.
__device__ __forceinline__ void gemm_epilogue(f32x4 acc[2][4], int row0, int quad,
        int l16, int nb, const float* __restrict__ a_src,
        const float* __restrict__ a_dst, u8* __restrict__ ht8,
        float* __restrict__ asrc, float* __restrict__ adst) {
    #pragma unroll
    for (int m = 0; m < 2; ++m) {
        #pragma unroll
        for (int r = 0; r < 4; ++r) {
            int row = row0 + m * 16 + quad * 4 + r;
            if (row < N_NODES) {
                u8* hr = ht8 + (size_t)row * HC;
                #pragma unroll
                for (int n = 0; n < 4; ++n)
                    hr[nb + n * 16 + l16] = f2fp8(acc[m][n][r]);
            }
        }
    }
    const int hA = nb >> 5;
    const float sA0 = a_src[hA * 32 + l16],       sA1 = a_src[hA * 32 + 16 + l16];
    const float sB0 = a_src[(hA + 1) * 32 + l16], sB1 = a_src[(hA + 1) * 32 + 16 + l16];
    const float dA0 = a_dst[hA * 32 + l16],       dA1 = a_dst[hA * 32 + 16 + l16];
    const float dB0 = a_dst[(hA + 1) * 32 + l16], dB1 = a_dst[(hA + 1) * 32 + 16 + l16];
    #pragma unroll
    for (int m = 0; m < 2; ++m) {
        #pragma unroll
        for (int r = 0; r < 4; ++r) {
            float pa = acc[m][0][r] * sA0 + acc[m][1][r] * sA1;
            float pb = acc[m][2][r] * sB0 + acc[m][3][r] * sB1;
            float qa = acc[m][0][r] * dA0 + acc[m][1][r] * dA1;
            float qb = acc[m][2][r] * dB0 + acc[m][3][r] * dB1;
            #pragma unroll
            for (int off = 1; off < 16; off <<= 1) {
                pa += __shfl_xor(pa, off, 64);
                pb += __shfl_xor(pb, off, 64);
                qa += __shfl_xor(qa, off, 64);
                qb += __shfl_xor(qb, off, 64);
            }
            int row = row0 + m * 16 + quad * 4 + r;
            if (l16 == 0 && row < N_NODES) {
                asrc[row * NHEAD + hA]     = pa;
                asrc[row * NHEAD + hA + 1] = pb;
                adst[row * NHEAD + hA]     = qa;
                adst[row * NHEAD + hA + 1] = qb;
            }
        }
    }
}

// ================= GEMM1: ht8 = fp8(x @ W1) + fused alpha, LDS-staged A.
// Block coalesced-loads its 32x256 fp32 x-tile (contiguous 32KB), packs bf16
// into 16KB LDS with XOR swizzle (G4: byte ^= (row&7)<<4), one barrier, MFMA.
__global__ __launch_bounds__(256) void gemm1_mfma(const float* __restrict__ x,
        const u16* __restrict__ Wt, const float* __restrict__ a_src,
        const float* __restrict__ a_dst, u8* __restrict__ ht8,
        float* __restrict__ asrc, float* __restrict__ adst) {
    __shared__ u16 As[32 * 256];          // 16 KB bf16, swizzled
    const int row0 = blockIdx.x * 32;
    const int t    = threadIdx.x;

    {   // stage: 8 threads per row, float4-contiguous per wave
        const int r   = t >> 3;                       // 0..31
        const int sub = t & 7;
        const int gr  = min(row0 + r, N_NODES - 1);   // clamp pad rows
        const float4* xr = (const float4*)(x + (size_t)gr * F_IN);
        const int sw = (r & 7) << 4;
        char* Ar = (char*)As + r * 512;
        #pragma unroll
        for (int i = 0; i < 8; ++i) {
            int f4 = i * 8 + sub;                     // float4 idx 0..63
            float4 v = xr[f4];
            u32 lo = (u32)f2bf(v.x) | ((u32)f2bf(v.y) << 16);
            u32 hi = (u32)f2bf(v.z) | ((u32)f2bf(v.w) << 16);
            *(uint2*)(Ar + ((f4 * 8) ^ sw)) = make_uint2(lo, hi);
        }
    }
    __syncthreads();

    const int wave = t >> 6;
    const int lane = t & 63;
    const int l16  = lane & 15;
    const int quad = lane >> 4;
    const int nb   = wave * 64;
    const int swr  = (l16 & 7) << 4;
    const char* Ab = (const char*)As;

    f32x4 acc[2][4];
    #pragma unroll
    for (int m = 0; m < 2; ++m)
        #pragma unroll
        for (int n = 0; n < 4; ++n) acc[m][n] = (f32x4){0.f, 0.f, 0.f, 0.f};

    const u16* bp = Wt + (size_t)(nb + l16) * F_IN;   // N-tile stride 16*F_IN

    #pragma unroll 1
    for (int k0 = 0; k0 < F_IN; k0 += 32) {
        const int ko = k0 + quad * 8;
        bf16x8 a0 = *(const bf16x8*)(Ab + l16 * 512 + ((ko * 2) ^ swr));
        bf16x8 a1 = *(const bf16x8*)(Ab + (16 + l16) * 512 + ((ko * 2) ^ swr));
        bf16x8 b0 = *(const bf16x8*)(bp + 0 * 16 * F_IN + ko);
        bf16x8 b1 = *(const bf16x8*)(bp + 1 * 16 * F_IN + ko);
        bf16x8 b2 = *(const bf16x8*)(bp + 2 * 16 * F_IN + ko);
        bf16x8 b3 = *(const bf16x8*)(bp + 3 * 16 * F_IN + ko);
        acc[0][0] = __builtin_amdgcn_mfma_f32_16x16x32_bf16(a0, b0, acc[0][0], 0, 0, 0);
        acc[0][1] = __builtin_amdgcn_mfma_f32_16x16x32_bf16(a0, b1, acc[0][1], 0, 0, 0);
        acc[0][2] = __builtin_amdgcn_mfma_f32_16x16x32_bf16(a0, b2, acc[0][2], 0, 0, 0);
        acc[0][3] = __builtin_amdgcn_mfma_f32_16x16x32_bf16(a0, b3, acc[0][3], 0, 0, 0);
        acc[1][0] = __builtin_amdgcn_mfma_f32_16x16x32_bf16(a1, b0, acc[1][0], 0, 0, 0);
        acc[1][1] = __builtin_amdgcn_mfma_f32_16x16x32_bf16(a1, b1, acc[1][1], 0, 0, 0);
        acc[1][2] = __builtin_amdgcn_mfma_f32_16x16x32_bf16(a1, b2, acc[1][2], 0, 0, 0);
        acc[1][3] = __builtin_amdgcn_mfma_f32_16x16x32_bf16(a1, b3, acc[1][3], 0, 0, 0);
    }
    gemm_epilogue(acc, row0, quad, l16, nb, a_src, a_dst, ht8, asrc, adst);
}

// ================= GEMM2: ht8 = fp8(hmb @ W2) + fused alpha, K=32 one step
__global__ __launch_bounds__(256) void gemm2_mfma(const u16* __restrict__ hmb,
        const u16* __restrict__ W2t, const float* __restrict__ a_src,
        const float* __restrict__ a_dst, u8* __restrict__ ht8,
        float* __restrict__ asrc, float* __restrict__ adst) {
    const int row0 = blockIdx.x * 32;
    const int t    = threadIdx.x;
    const int wave = t >> 6;
    const int lane = t & 63;
    const int l16  = lane & 15;
    const int quad = lane >> 4;
    const int nb   = wave * 64;
    const int ko   = quad * 8;

    const u16* a0p = hmb + (size_t)(row0 + l16) * CH;
    const u16* a1p = a0p + 16 * CH;
    const u16* bp  = W2t + (size_t)(nb + l16) * CH;

    bf16x8 a0 = *(const bf16x8*)(a0p + ko);
    bf16x8 a1 = *(const bf16x8*)(a1p + ko);
    bf16x8 b0 = *(const bf16x8*)(bp + 0 * 16 * CH + ko);
    bf16x8 b1 = *(const bf16x8*)(bp + 1 * 16 * CH + ko);
    bf16x8 b2 = *(const bf16x8*)(bp + 2 * 16 * CH + ko);
    bf16x8 b3 = *(const bf16x8*)(bp + 3 * 16 * CH + ko);

    f32x4 z = (f32x4){0.f, 0.f, 0.f, 0.f};
    f32x4 acc[2][4];
    acc[0][0] = __builtin_amdgcn_mfma_f32_16x16x32_bf16(a0, b0, z, 0, 0, 0);
    acc[0][1] = __builtin_amdgcn_mfma_f32_16x16x32_bf16(a0, b1, z, 0, 0, 0);
    acc[0][2] = __builtin_amdgcn_mfma_f32_16x16x32_bf16(a0, b2, z, 0, 0, 0);
    acc[0][3] = __builtin_amdgcn_mfma_f32_16x16x32_bf16(a0, b3, z, 0, 0, 0);
    acc[1][0] = __builtin_amdgcn_mfma_f32_16x16x32_bf16(a1, b0, z, 0, 0, 0);
    acc[1][1] = __builtin_amdgcn_mfma_f32_16x16x32_bf16(a1, b1, z, 0, 0, 0);
    acc[1][2] = __builtin_amdgcn_mfma_f32_16x16x32_bf16(a1, b2, z, 0, 0, 0);
    acc[1][3] = __builtin_amdgcn_mfma_f32_16x16x32_bf16(a1, b3, z, 0, 0, 0);

    gemm_epilogue(acc, row0, quad, l16, nb, a_src, a_dst, ht8, asrc, adst);
}

// ================= fused attention: one WAVE per dst node, QUARTER per edge.
// Triple-confirmed r3/r7 body (57.3us): uniform trips, pk_fma, u16 csr,
// depth-2 rotating prefetch, bucket CSR (p0 = dst*CAP, p1 = p0 + deg).
__global__ __launch_bounds__(256) void attn_kernel(const int* __restrict__ degp,
        const u16* __restrict__ csr_src, const float* __restrict__ asrc,
        const float* __restrict__ adst, const u8* __restrict__ ht8,
        const float* __restrict__ b, u16* __restrict__ out) {
    const int wid = (blockIdx.x * 256 + threadIdx.x) >> 6;   // dst node
    if (wid >= N_NODES) return;
    const int dst  = wid;
    const int lane = threadIdx.x & 63;
    const int q    = lane >> 4;          // quarter -> edge offset
    const int l16  = lane & 15;
    const int h    = l16 >> 1;           // owned head
    const float ad_own = adst[dst * NHEAD + h];
    const u8* hbase = ht8 + l16 * 16;    // this lane's 16B slice of each row

    f32x2 acc2[8];
    #pragma unroll
    for (int i = 0; i < 8; ++i) acc2[i] = (f32x2){0.f, 0.f};
    float wsum = 0.f;

    const int cnt = min(degp[dst], CAP);
    const int p0 = dst * CAP, p1 = p0 + cnt;
    const int nt = (cnt + 7) >> 3;       // uniform trips (8 edges per trip)

    float asA = -1e30f, asB = -1e30f;
    uint4 hvA = make_uint4(0u, 0u, 0u, 0u), hvB = make_uint4(0u, 0u, 0u, 0u);
    int e = p0 + q;                      // this quarter's edges: stride 4
    if (e < p1) {
        int s = (int)csr_src[e];
        asA = asrc[s * NHEAD + h];
        hvA = *(const uint4*)(hbase + ((size_t)s << 8));
    }
    if (e + 4 < p1) {
        int s = (int)csr_src[e + 4];
        asB = asrc[s * NHEAD + h];
        hvB = *(const uint4*)(hbase + ((size_t)s << 8));
    }

    for (int it = 0; it < nt; ++it) {
        float aA = asA; uint4 hA = hvA;
        float aB = asB; uint4 hB = hvB;
        asA = -1e30f; asB = -1e30f;
        if (e + 8 < p1) {                 // prefetch next trip (predicated)
            int s = (int)csr_src[e + 8];
            asA = asrc[s * NHEAD + h];
            hvA = *(const uint4*)(hbase + ((size_t)s << 8));
        }
        if (e + 12 < p1) {
            int s = (int)csr_src[e + 12];
            asB = asrc[s * NHEAD + h];
            hvB = *(const uint4*)(hbase + ((size_t)s << 8));
        }
        {   // consume A (edge e); invalid slots: w==0, finite hv -> no-op
            float x = aA + ad_own;
            x = x > 0.f ? x : NEG_SLOPE * x;
            float w = __expf(x);
            wsum += w;
            f32x2 w2; w2.x = w; w2.y = w;
            acc2[0] = __builtin_elementwise_fma(w2, __builtin_amdgcn_cvt_pk_f32_fp8(hA.x, false), acc2[0]);
            acc2[1] = __builtin_elementwise_fma(w2, __builtin_amdgcn_cvt_pk_f32_fp8(hA.x, true ), acc2[1]);
            acc2[2] = __builtin_elementwise_fma(w2, __builtin_amdgcn_cvt_pk_f32_fp8(hA.y, false), acc2[2]);
            acc2[3] = __builtin_elementwise_fma(w2, __builtin_amdgcn_cvt_pk_f32_fp8(hA.y, true ), acc2[3]);
            acc2[4] = __builtin_elementwise_fma(w2, __builtin_amdgcn_cvt_pk_f32_fp8(hA.z, false), acc2[4]);
            acc2[5] = __builtin_elementwise_fma(w2, __builtin_amdgcn_cvt_pk_f32_fp8(hA.z, true ), acc2[5]);
            acc2[6] = __builtin_elementwise_fma(w2, __builtin_amdgcn_cvt_pk_f32_fp8(hA.w, false), acc2[6]);
            acc2[7] = __builtin_elementwise_fma(w2, __builtin_amdgcn_cvt_pk_f32_fp8(hA.w, true ), acc2[7]);
        }
        {   // consume B (edge e+4)
            float x = aB + ad_own;
            x = x > 0.f ? x : NEG_SLOPE * x;
            float w = __expf(x);
            wsum += w;
            f32x2 w2; w2.x = w; w2.y = w;
            acc2[0] = __builtin_elementwise_fma(w2, __builtin_amdgcn_cvt_pk_f32_fp8(hB.x, false), acc2[0]);
            acc2[1] = __builtin_elementwise_fma(w2, __builtin_amdgcn_cvt_pk_f32_fp8(hB.x, true ), acc2[1]);
            acc2[2] = __builtin_elementwise_fma(w2, __builtin_amdgcn_cvt_pk_f32_fp8(hB.y, false), acc2[2]);
            acc2[3] = __builtin_elementwise_fma(w2, __builtin_amdgcn_cvt_pk_f32_fp8(hB.y, true ), acc2[3]);
            acc2[4] = __builtin_elementwise_fma(w2, __builtin_amdgcn_cvt_pk_f32_fp8(hB.z, false), acc2[4]);
            acc2[5] = __builtin_elementwise_fma(w2, __builtin_amdgcn_cvt_pk_f32_fp8(hB.z, true ), acc2[5]);
            acc2[6] = __builtin_elementwise_fma(w2, __builtin_amdgcn_cvt_pk_f32_fp8(hB.w, false), acc2[6]);
            acc2[7] = __builtin_elementwise_fma(w2, __builtin_amdgcn_cvt_pk_f32_fp8(hB.w, true ), acc2[7]);
        }
        e += 8;
    }

    // ---- fold the four quarters (same (h,chblk), disjoint edges) ----
    #pragma unroll
    for (int i = 0; i < 8; ++i) {
        acc2[i].x += __shfl_xor(acc2[i].x, 16, 64);
        acc2[i].y += __shfl_xor(acc2[i].y, 16, 64);
        acc2[i].x += __shfl_xor(acc2[i].x, 32, 64);
        acc2[i].y += __shfl_xor(acc2[i].y, 32, 64);
    }
    wsum += __shfl_xor(wsum, 16, 64);
    wsum += __shfl_xor(wsum, 32, 64);

    // ---- per-head softmax normalize (v_pk_mul) ----
    float winv = 1.0f / wsum;
    f32x2 winv2; winv2.x = winv; winv2.y = winv;
    #pragma unroll
    for (int i = 0; i < 8; ++i) acc2[i] *= winv2;

    // ---- sum over heads: lane = 2h + blk, fold bits 1..3 ----
    #pragma unroll
    for (int i = 0; i < 8; ++i) {
        acc2[i].x += __shfl_xor(acc2[i].x, 2, 64);
        acc2[i].y += __shfl_xor(acc2[i].y, 2, 64);
        acc2[i].x += __shfl_xor(acc2[i].x, 4, 64);
        acc2[i].y += __shfl_xor(acc2[i].y, 4, 64);
        acc2[i].x += __shfl_xor(acc2[i].x, 8, 64);
        acc2[i].y += __shfl_xor(acc2[i].y, 8, 64);
    }

    // ---- lane 0: channels 0..15, lane 1: channels 16..31 ----
    if (lane < 2) {
        const int c0 = lane * 16;
        const float4* bp4 = (const float4*)(b + c0);
        float4 b0 = bp4[0], b1 = bp4[1], b2 = bp4[2], b3 = bp4[3];
        float bb[16] = {b0.x, b0.y, b0.z, b0.w, b1.x, b1.y, b1.z, b1.w,
                        b2.x, b2.y, b2.z, b2.w, b3.x, b3.y, b3.z, b3.w};
        u32 d[8];
        #pragma unroll
        for (int i = 0; i < 8; ++i) {
            float v0 = acc2[i].x * 0.125f + bb[2 * i];
            float v1 = acc2[i].y * 0.125f + bb[2 * i + 1];
            v0 = v0 > 0.f ? v0 : (__expf(v0) - 1.f);
            v1 = v1 > 0.f ? v1 : (__expf(v1) - 1.f);
            d[i] = (u32)f2bf(v0) | ((u32)f2bf(v1) << 16);
        }
        uint4* op = (uint4*)(out + (size_t)dst * CH + c0);
        op[0] = make_uint4(d[0], d[1], d[2], d[3]);
        op[1] = make_uint4(d[4], d[5], d[6], d[7]);
    }
}

// ================= output head: 4 nodes/block (1 wave each), log_softmax
__global__ __launch_bounds__(256) void out_kernel(const u16* __restrict__ hf,
        const float* __restrict__ Wo, const float* __restrict__ bo,
        float* __restrict__ out) {
    const int wave = threadIdx.x >> 6;
    const int lane = threadIdx.x & 63;
    const int n    = blockIdx.x * 4 + wave;
    __shared__ float hs[4][CH];
    if (n < N_NODES && lane < CH) hs[wave][lane] = bflo((u32)hf[n * CH + lane]);
    __syncthreads();
    if (n >= N_NODES) return;
    float logit = -INFINITY;
    if (lane < OUT_C) {
        float a = bo[lane];
        #pragma unroll
        for (int k = 0; k < CH; ++k) a += hs[wave][k] * Wo[k * OUT_C + lane];
        logit = a;
    }
    float m = logit;
    #pragma unroll
    for (int off = 32; off; off >>= 1) m = fmaxf(m, __shfl_xor(m, off, 64));
    float ex = (lane < OUT_C) ? __expf(logit - m) : 0.f;
    float ssum = ex;
    #pragma unroll
    for (int off = 32; off; off >>= 1) ssum += __shfl_xor(ssum, off, 64);
    if (lane < OUT_C) out[(size_t)n * OUT_C + lane] = logit - m - __logf(ssum);
}

extern "C" void kernel_launch(void* const* d_in, const int* in_sizes, int n_in,
                              void* d_out, int out_size, void* d_ws, size_t ws_size,
                              hipStream_t stream) {
    const float* x      = (const float*)d_in[0];
    const int*   ei     = (const int*)  d_in[1];
    const float* W1     = (const float*)d_in[2];
    const float* a_src1 = (const float*)d_in[3];
    const float* a_dst1 = (const float*)d_in[4];
    const float* b1     = (const float*)d_in[5];
    const float* W2     = (const float*)d_in[6];
    const float* a_src2 = (const float*)d_in[7];
    const float* a_dst2 = (const float*)d_in[8];
    const float* b2     = (const float*)d_in[9];
    const float* Wo     = (const float*)d_in[10];
    const float* bo     = (const float*)d_in[11];
    float* out = (float*)d_out;

    // workspace carve-up (256B-aligned)
    char* ws = (char*)d_ws;
    size_t off = 0;
    auto carve = [&](size_t bytes) { char* p = ws + off; off += (bytes + 255) & ~(size_t)255; return p; };
    u8*    ht8     = (u8*)   carve((size_t)N_NODES * HC);          // 12.8 MB (fp8, head-major)
    u16*   Wt      = (u16*)  carve((size_t)HC * F_IN * 2);         // 128 KB (bf16 W1^T)
    u16*   W2t     = (u16*)  carve((size_t)HC * CH * 2);           // 16 KB (bf16 W2^T)
    float* asrc    = (float*)carve((size_t)N_NODES * NHEAD * 4);   // 1.6 MB
    float* adst    = (float*)carve((size_t)N_NODES * NHEAD * 4);
    u16*   hmid    = (u16*)  carve((size_t)N_PAD * CH * 2);        // 3.2 MB (bf16)
    u16*   hout    = (u16*)  carve((size_t)N_NODES * CH * 2);      // 3.2 MB (bf16)
    int*   cursor  = (int*)  carve((size_t)N_NODES * 4);           // doubles as deg
    u16*   csr_src = (u16*)  carve((size_t)N_NODES * CAP * 2);     // 6.4 MB buckets

    const int g_prep  = G_BIN + G_WCVT + G_WCVT2;            // 3616
    const int g_attn  = (N_NODES * 64 + 255) / 256;          // 12500 (wave/dst)
    const int g_out   = (N_NODES + 3) / 4;                   // 12500

    // ---------- prep: one-pass bucket CSR + W transposes ----------
    (void)hipMemsetAsync(cursor, 0, (size_t)N_NODES * 4, stream);
    prep_kernel<<<g_prep, 256, 0, stream>>>(ei, cursor, csr_src, W1, Wt, W2, W2t);

    // ---------- layer 1 (alpha fused into gemm epilogue) ----------
    gemm1_mfma<<<G_GEMM, 256, 0, stream>>>(x, Wt, a_src1, a_dst1, ht8, asrc, adst);
    attn_kernel<<<g_attn, 256, 0, stream>>>(cursor, csr_src, asrc, adst, ht8, b1, hmid);

    // ---------- layer 2 ----------
    gemm2_mfma<<<G_GEMM, 256, 0, stream>>>(hmid, W2t, a_src2, a_dst2, ht8, asrc, adst);
    attn_kernel<<<g_attn, 256, 0, stream>>>(cursor, csr_src, asrc, adst, ht8, b2, hout);

    // ---------- output head ----------
    out_kernel<<<g_out, 256, 0, stream>>>(hout, Wo, bo, out);
}